// Round 8
// baseline (1331.918 us; speedup 1.0000x reference)
//
#include <hip/hip_runtime.h>
#include <math.h>

// ---------------------------------------------------------------------------
// CapsuleNet forward. prim-caps conv = bf16 MFMA GEMM, 3-term hi/lo split
// (acc += Ah*Bh + Ah*Bl + Al*Bh).  M=18432  N=256  K=20736.
// GEMM: BM=64 BN=256 BK=32, 256 thr (4 waves, wave-tile 64x64), LDS 80 KB
// (double-buffered), 2 blocks/CU.  2-phase pipeline: stage(next) ->
// s_waitcnt vmcnt(10) -> raw barrier -> MFMA(cur) -> barrier.  K-split 4
// (ksp INNER in bid for y0 L3 locality), unsafeAtomicAdd accumulation.
// ---------------------------------------------------------------------------

typedef float f32x4 __attribute__((ext_vector_type(4)));
typedef short s16x8 __attribute__((ext_vector_type(8)));

#define GLD16(g, l)                                             \
  __builtin_amdgcn_global_load_lds(                             \
      (const __attribute__((address_space(1))) void*)(g),       \
      (__attribute__((address_space(3))) void*)(l), 16, 0, 0)

__device__ __forceinline__ ushort f2bf(float f) {   // RNE f32 -> bf16 bits
  unsigned u = __float_as_uint(f);
  u += 0x7FFFu + ((u >> 16) & 1u);
  return (ushort)(u >> 16);
}
__device__ __forceinline__ float bf2f(ushort h) {
  return __uint_as_float(((unsigned)h) << 16);
}

// ---- 0. zero the accumulator buffer (ws is poisoned every launch)
__global__ __launch_bounds__(256) void zero_part_kernel(float* __restrict__ p) {
  uint4 z = {0u, 0u, 0u, 0u};
  uint4* dst = (uint4*)p + (size_t)blockIdx.x * 1024 + threadIdx.x;
  #pragma unroll
  for (int i = 0; i < 4; ++i) dst[i * 256] = z;
}

// ---- 1. weight split+transpose via LDS: Wt[co][p][ci] hi/lo <- w[co][ci][p]
__global__ __launch_bounds__(256) void wt_split_kernel(
    const float* __restrict__ w, ushort* __restrict__ wth,
    ushort* __restrict__ wtl) {
  __shared__ float sb[20736];
  const int co = blockIdx.x;
  const int t  = threadIdx.x;
  const float* src = w + (size_t)co * 20736;
  for (int j = t; j < 20736; j += 256) sb[j] = src[j];   // coalesced
  __syncthreads();
  ushort* dh = wth + (size_t)co * 20736;
  ushort* dl = wtl + (size_t)co * 20736;
  for (int j = t; j < 20736; j += 256) {   // j = p*256 + ci  (coalesced writes)
    const int p  = j >> 8;
    const int ci = j & 255;
    const float v = sb[ci * 81 + p];       // stride-81: conflict-free (odd)
    const ushort h = f2bf(v);
    const ushort l = f2bf(v - bf2f(h));
    dh[j] = h;
    dl[j] = l;
  }
}

// ---- 2. conv0 stem -> y0 NHWC as bf16 hi/lo
__global__ __launch_bounds__(256) void conv0_kernel(
    const float* __restrict__ x, const float* __restrict__ w,
    const float* __restrict__ bias, ushort* __restrict__ y0h,
    ushort* __restrict__ y0l) {
  __shared__ float wl[256 * 81];
  __shared__ float xl[784];
  const int t   = threadIdx.x;
  const int img = blockIdx.x;
  for (int j = t; j < 256 * 81; j += 256) wl[j] = w[j];
  for (int j = t; j < 784; j += 256) xl[j] = x[img * 784 + j];
  __syncthreads();
  const float bv = bias[t];
  ushort* yh = y0h + (size_t)img * 400 * 256 + t;
  ushort* yl = y0l + (size_t)img * 400 * 256 + t;
  for (int oy = 0; oy < 20; ++oy) {
    float acc[20];
    #pragma unroll
    for (int ox = 0; ox < 20; ++ox) acc[ox] = bv;
    for (int ky = 0; ky < 9; ++ky) {
      float xr[28];
      #pragma unroll
      for (int j = 0; j < 28; ++j) xr[j] = xl[(oy + ky) * 28 + j];
      #pragma unroll
      for (int kx = 0; kx < 9; ++kx) {
        const float wv = wl[t * 81 + ky * 9 + kx];
        #pragma unroll
        for (int ox = 0; ox < 20; ++ox)
          acc[ox] = fmaf(wv, xr[ox + kx], acc[ox]);
      }
    }
    #pragma unroll
    for (int ox = 0; ox < 20; ++ox) {
      const float v = acc[ox] > 0.f ? acc[ox] : 0.f;
      const ushort h = f2bf(v);
      const ushort l = f2bf(v - bf2f(h));
      yh[(size_t)(oy * 20 + ox) * 256] = h;
      yl[(size_t)(oy * 20 + ox) * 256] = l;
    }
  }
}

// ---- 3. MFMA GEMM, 2-phase double-buffered pipeline.
// grid = mt(288) x ksp(4), ksp inner; 256 threads (4 waves).
__global__ __launch_bounds__(256, 2) void prim_gemm_mfma(
    const ushort* __restrict__ y0h, const ushort* __restrict__ y0l,
    const ushort* __restrict__ wth, const ushort* __restrict__ wtl,
    float* __restrict__ part) {
  __shared__ ushort Ah[2][64 * 32], Al[2][64 * 32];     //  8 KB each pair
  __shared__ ushort Bh[2][256 * 32], Bl[2][256 * 32];   // 32 KB each pair

  const int t   = threadIdx.x;
  const int bid = blockIdx.x;
  const int mt  = bid >> 2;             // ksp inner: 4 siblings share y0 rows
  const int ksp = bid & 3;
  const int r0  = mt * 64;
  const int ks0 = ksp * 162, ksend = ks0 + 162;   // 648 BK-32 chunks total

  // A staging source: thread t -> row ar=t>>2, phys slot t&3 holds chunk ac
  const int ar = t >> 2;
  const int ac = (t & 3) ^ ((t >> 3) & 3);
  int asrc;
  {
    const int gr  = r0 + ar;
    const int img = gr / 36;
    const int s   = gr - img * 36;
    const int oy  = s / 6, ox = s - oy * 6;
    asrc = (img * 400 + oy * 40 + ox * 2) * 256 + ac * 8;
  }
  // B staging: job i covers rows [i*64, i*64+64)
  int bsrc[4];
  #pragma unroll
  for (int i = 0; i < 4; ++i) {
    const int j  = i * 256 + t;
    const int br = j >> 2;
    const int bc = (j & 3) ^ ((j >> 3) & 3);
    bsrc[i] = br * 20736 + bc * 8;
  }

  const int lane = t & 63, w = t >> 6;
  const int g = lane >> 4, lr = lane & 15;
  const int xg = ((g ^ ((lr >> 1) & 3)) << 4);    // frag-read in-row byte off

  f32x4 acc[4][4];
  #pragma unroll
  for (int mi = 0; mi < 4; ++mi)
    #pragma unroll
    for (int ni = 0; ni < 4; ++ni)
      acc[mi][ni] = (f32x4){0.f, 0.f, 0.f, 0.f};

  // stage one BK-32 chunk kk into buffer d (10 GLD16 per thread)
  #define STAGE(d, kk)                                                        \
    {                                                                         \
      const int seg_ = (kk) >> 3;                                             \
      const int ci0_ = ((kk) & 7) << 5;                                       \
      const int ky_  = seg_ / 9, kx_ = seg_ - ky_ * 9;                        \
      const int ao_  = (ky_ * 20 + kx_) * 256 + ci0_;                         \
      const int bo_  = seg_ * 256 + ci0_;                                     \
      GLD16(y0h + asrc + ao_, (char*)Ah[d] + w * 1024);                       \
      GLD16(y0l + asrc + ao_, (char*)Al[d] + w * 1024);                       \
      _Pragma("unroll")                                                       \
      for (int i_ = 0; i_ < 4; ++i_) {                                        \
        GLD16(wth + bsrc[i_] + bo_, (char*)Bh[d] + i_ * 4096 + w * 1024);     \
        GLD16(wtl + bsrc[i_] + bo_, (char*)Bl[d] + i_ * 4096 + w * 1024);     \
      }                                                                       \
    }

  STAGE(0, ks0);                         // prologue

  for (int kk = ks0; kk < ksend; ++kk) {
    const int c = (kk - ks0) & 1;
    if (kk + 1 < ksend) {
      STAGE(c ^ 1, kk + 1);              // issue next tile's loads
      asm volatile("s_waitcnt vmcnt(10)" ::: "memory");  // cur tile complete
    } else {
      asm volatile("s_waitcnt vmcnt(0)" ::: "memory");
    }
    __builtin_amdgcn_s_barrier();        // cur buffer fully written, CU-wide
    asm volatile("" ::: "memory");

    const ushort* AhC = Ah[c];
    const ushort* AlC = Al[c];
    const ushort* BhC = Bh[c];
    const ushort* BlC = Bl[c];
    s16x8 bhv[4], blv[4];
    #pragma unroll
    for (int ni = 0; ni < 4; ++ni) {
      const int off = (w * 64 + ni * 16 + lr) * 64 + xg;
      bhv[ni] = *(const s16x8*)((const char*)BhC + off);
      blv[ni] = *(const s16x8*)((const char*)BlC + off);
    }
    __builtin_amdgcn_s_setprio(1);
    #pragma unroll
    for (int mi = 0; mi < 4; ++mi) {
      const int off = (mi * 16 + lr) * 64 + xg;
      const s16x8 ahv = *(const s16x8*)((const char*)AhC + off);
      const s16x8 alv = *(const s16x8*)((const char*)AlC + off);
      #pragma unroll
      for (int ni = 0; ni < 4; ++ni) {
        acc[mi][ni] = __builtin_amdgcn_mfma_f32_16x16x32_bf16(ahv, bhv[ni], acc[mi][ni], 0, 0, 0);
        acc[mi][ni] = __builtin_amdgcn_mfma_f32_16x16x32_bf16(ahv, blv[ni], acc[mi][ni], 0, 0, 0);
        acc[mi][ni] = __builtin_amdgcn_mfma_f32_16x16x32_bf16(alv, bhv[ni], acc[mi][ni], 0, 0, 0);
      }
    }
    __builtin_amdgcn_s_setprio(0);
    asm volatile("" ::: "memory");
    __builtin_amdgcn_s_barrier();        // all waves done reading buf c
  }
  #undef STAGE

  // epilogue: part[(img*256+co)*36 + s] += acc  (C/D: col=lane&15, row=g*4+q)
  #pragma unroll
  for (int mi = 0; mi < 4; ++mi) {
    #pragma unroll
    for (int q = 0; q < 4; ++q) {
      const int gr  = r0 + mi * 16 + g * 4 + q;
      const int img = gr / 36;
      const int s   = gr - img * 36;
      float* prow = part + (size_t)img * 9216 + s;
      #pragma unroll
      for (int ni = 0; ni < 4; ++ni) {
        const int co = w * 64 + ni * 16 + lr;
        unsafeAtomicAdd(&prow[co * 36], acc[mi][ni][q]);
      }
    }
  }
}

// ---- 4. bias + squash + x_hat einsum: thread per (b,i)
__global__ __launch_bounds__(256) void xhat_kernel(
    const float* __restrict__ part, const float* __restrict__ bias,
    const float* __restrict__ dw, float* __restrict__ xhat) {
  const int gid = blockIdx.x * 256 + threadIdx.x;
  const int b = gid / 1152;
  const int i = gid - b * 1152;
  const size_t base = (size_t)b * 9216 + i * 8;
  const f32x4 s0 = *(const f32x4*)(part + base);
  const f32x4 s1 = *(const f32x4*)(part + base + 4);
  float u[8];
  #pragma unroll
  for (int d = 0; d < 4; ++d) u[d] = s0[d] + bias[(i * 8 + d) / 36];
  #pragma unroll
  for (int d = 0; d < 4; ++d) u[4 + d] = s1[d] + bias[(i * 8 + 4 + d) / 36];
  float n2 = 0.f;
  #pragma unroll
  for (int d = 0; d < 8; ++d) n2 += u[d] * u[d];
  const float nn = sqrtf(n2);
  const float sc = n2 / (1.f + n2) / (nn + 1e-8f);
  #pragma unroll
  for (int d = 0; d < 8; ++d) u[d] *= sc;
  #pragma unroll
  for (int o = 0; o < 10; ++o) {
    const float4 w0 = *(const float4*)(dw + (size_t)(o * 1152 + i) * 8);
    const float4 w1 = *(const float4*)(dw + (size_t)(o * 1152 + i) * 8 + 4);
    float d = w0.x * u[0];
    d = fmaf(w0.y, u[1], d);
    d = fmaf(w0.z, u[2], d);
    d = fmaf(w0.w, u[3], d);
    d = fmaf(w1.x, u[4], d);
    d = fmaf(w1.y, u[5], d);
    d = fmaf(w1.z, u[6], d);
    d = fmaf(w1.w, u[7], d);
    xhat[(size_t)(b * 10 + o) * 1152 + i] = d;
  }
}

// ---- 5. dynamic routing: one block per batch image
__global__ __launch_bounds__(256) void routing_kernel(
    const float* __restrict__ xhat, float* __restrict__ out) {
  __shared__ float xh[11520];
  __shared__ float bl[11520];
  __shared__ float red[48];
  __shared__ float vbc[10];
  const int t = threadIdx.x;
  const int b = blockIdx.x;
  for (int j = t; j < 11520; j += 256) {
    xh[j] = xhat[(size_t)b * 11520 + j];
    bl[j] = 0.f;
  }
  __syncthreads();
  const int lane = t & 63, wv = t >> 6;
  float vout[10];
  for (int it = 0; it < 3; ++it) {
    float sp[10];
    #pragma unroll
    for (int o = 0; o < 10; ++o) sp[o] = 0.f;
    for (int i = t; i < 1152; i += 256) {
      float e[10];
      float mx = bl[i];
      #pragma unroll
      for (int o = 1; o < 10; ++o) mx = fmaxf(mx, bl[o * 1152 + i]);
      float se = 0.f;
      #pragma unroll
      for (int o = 0; o < 10; ++o) { e[o] = expf(bl[o * 1152 + i] - mx); se += e[o]; }
      const float inv = 1.f / se;
      #pragma unroll
      for (int o = 0; o < 10; ++o) sp[o] += e[o] * inv * xh[o * 1152 + i];
    }
    #pragma unroll
    for (int o = 0; o < 10; ++o) {
      float v = sp[o];
      #pragma unroll
      for (int d = 32; d > 0; d >>= 1) v += __shfl_xor(v, d, 64);
      if (lane == 0) red[o * 4 + wv] = v;
    }
    __syncthreads();
    if (t < 10) {
      const float s = red[t * 4] + red[t * 4 + 1] + red[t * 4 + 2] + red[t * 4 + 3];
      const float n = fabsf(s);
      const float sc = (n * n) / (1.f + n * n) / (n + 1e-8f);
      vbc[t] = sc * s;
    }
    __syncthreads();
    #pragma unroll
    for (int o = 0; o < 10; ++o) vout[o] = vbc[o];
    if (it < 2) {
      for (int i = t; i < 1152; i += 256) {
        #pragma unroll
        for (int o = 0; o < 10; ++o) bl[o * 1152 + i] += vout[o] * xh[o * 1152 + i];
      }
    }
    __syncthreads();
  }
  if (t < 10) out[b * 10 + t] = fabsf(vout[t]);
}

// ---------------------------------------------------------------------------
extern "C" void kernel_launch(void* const* d_in, const int* in_sizes, int n_in,
                              void* d_out, int out_size, void* d_ws, size_t ws_size,
                              hipStream_t stream) {
  const float* x   = (const float*)d_in[0];
  const float* c0w = (const float*)d_in[1];
  const float* c0b = (const float*)d_in[2];
  const float* pw  = (const float*)d_in[3];
  const float* pb  = (const float*)d_in[4];
  const float* dw  = (const float*)d_in[5];
  float* out = (float*)d_out;
  char* W = (char*)d_ws;

  // workspace layout (bytes), total 249,823,232:
  ushort* y0h  = (ushort*)(W);                    // 104,857,600
  ushort* y0l  = (ushort*)(W + 104857600);        // 104,857,600
  ushort* wth  = (ushort*)(W + 209715200);        //  10,616,832
  ushort* wtl  = (ushort*)(W + 220332032);        //  10,616,832
  float*  part = (float*)(W + 230948864);         //  18,874,368 (4,718,592 fp32)
  float*  xh   = (float*)(W);                     //  23,592,960 (over dead y0h)

  hipLaunchKernelGGL(wt_split_kernel, dim3(256), dim3(256), 0, stream, pw, wth, wtl);
  hipLaunchKernelGGL(conv0_kernel, dim3(512), dim3(256), 0, stream, x, c0w, c0b, y0h, y0l);
  hipLaunchKernelGGL(zero_part_kernel, dim3(1152), dim3(256), 0, stream, part);
  hipLaunchKernelGGL(prim_gemm_mfma, dim3(1152), dim3(256), 0, stream, y0h, y0l, wth, wtl, part);
  hipLaunchKernelGGL(xhat_kernel, dim3(2304), dim3(256), 0, stream, part, pb, dw, xh);
  hipLaunchKernelGGL(routing_kernel, dim3(512), dim3(256), 0, stream, xh, out);
}